// Round 4
// baseline (314.549 us; speedup 1.0000x reference)
//
#include <hip/hip_runtime.h>
#include <math.h>

#define F_NODES 16384
#define DEG 8
#define E_TOT (F_NODES * DEG)   // 131072
#define B 64
#define H 16
#define LAYERS 10
#define NPW 2                   // nodes per wave

typedef unsigned short bf16_t;

__device__ __forceinline__ bf16_t f32_to_bf16(float f)
{
    unsigned u = __float_as_uint(f);
    u = (u + 0x7FFFu + ((u >> 16) & 1u)) >> 16;   // round-to-nearest-even
    return (bf16_t)u;
}
__device__ __forceinline__ float bf16_to_f32(bf16_t h)
{
    return __uint_as_float((unsigned)h << 16);
}
// packed-pair unpack: elem0 = bits[15:0], elem1 = bits[31:16]
__device__ __forceinline__ float bfu_lo(unsigned u) { return __uint_as_float(u << 16); }
__device__ __forceinline__ float bfu_hi(unsigned u) { return __uint_as_float(u & 0xFFFF0000u); }

__device__ __forceinline__ float fast_elu(float x)
{
    float e = __builtin_amdgcn_exp2f(x * 1.44269504088896340736f) - 1.0f;
    return x > 0.0f ? x : e;
}

// ---------------------------------------------------------------------------
// Transpose x0 (B, E) fp32 -> x0T16 (E, B) bf16 (only copy of the residual).
// ---------------------------------------------------------------------------
__global__ __launch_bounds__(256) void transpose_in_kernel(
    const float* __restrict__ x0, bf16_t* __restrict__ xT16)
{
    __shared__ float tile[64 * 65];
    const int e0 = blockIdx.x * 64;
    const int c  = threadIdx.x & 63;
    const int r  = threadIdx.x >> 6;

    #pragma unroll
    for (int i = 0; i < 16; ++i) {
        const int b = r + i * 4;
        tile[c * 65 + b] = x0[(size_t)b * E_TOT + e0 + c];
    }
    __syncthreads();
    const int b = threadIdx.x & 63;
    #pragma unroll
    for (int i = 0; i < 16; ++i) {
        const int el = r + i * 4;
        xT16[(size_t)(e0 + el) * B + b] = f32_to_bf16(tile[el * 65 + b]);
    }
}

// inv[P[k]] = k  (P = flat in_ixs, a permutation of E)
__global__ __launch_bounds__(256) void build_inv_kernel(
    const int* __restrict__ in_ixs, int* __restrict__ inv)
{
    const int k = blockIdx.x * 256 + threadIdx.x;
    inv[in_ixs[k]] = k;
}

// Pack W1/W2 fp32 -> bf16 pairs (one dword = 2 consecutive weights).
__global__ __launch_bounds__(256) void pack_weights_kernel(
    const float* __restrict__ W1, const float* __restrict__ W2,
    unsigned* __restrict__ W1b, unsigned* __restrict__ W2b)
{
    const int i = blockIdx.x * 256 + threadIdx.x;
    float2 a = ((const float2*)W1)[i];
    W1b[i] = (unsigned)f32_to_bf16(a.x) | ((unsigned)f32_to_bf16(a.y) << 16);
    float2 c = ((const float2*)W2)[i];
    W2b[i] = (unsigned)f32_to_bf16(c.x) | ((unsigned)f32_to_bf16(c.y) << 16);
}

// ---------------------------------------------------------------------------
// One GSNN layer. z is PRE-PERMUTED (z[k] = x[P[k]]): sequential reads;
// the permutation is applied by scatter-stores via inv.
//   MODE 0: first  — gather bf16 x0T16[P[e]],           scatter bf16 z
//   MODE 1: middle — seq bf16 z in,                     scatter bf16 z
//   MODE 2: final  — seq bf16 z in,            fp32 (B,E) natural out
// v3: z/residual reads are ONE dwordx4 wave-load per 1-KB node block
// (16 B/lane) bounced through wave-private LDS (no barrier), replacing 16
// scalar 2-B loads — 8x fewer VMEM ops / 8x more bytes per miss slot.
// MODE 2 output goes through a padded LDS tile so stores are full lines.
// ---------------------------------------------------------------------------
template <int MODE>
__global__ __launch_bounds__(256, 4) void layer_kernel(
    const bf16_t*  __restrict__ zin,    // (E, B) bf16 pre-permuted
    const bf16_t*  __restrict__ x0T16,  // (E, B) bf16
    const unsigned* __restrict__ W1b,   // (F, H, DEG/2) packed
    const float*   __restrict__ b1,     // (F, H)
    const unsigned* __restrict__ W2b,   // (F, DEG, H/2) packed
    const float*   __restrict__ b2,     // (F, DEG)
    const int*     __restrict__ in_ixs, // (F, DEG) = P
    const int*     __restrict__ inv,    // (E)      = P^-1
    bf16_t* __restrict__ zout,          // (E, B) bf16 pre-permuted
    float*  __restrict__ out)           // (B, E) fp32 final
{
    // wave-private staging: [wave][node][z=0/r=1][lane] -> 16 KB/block
    __shared__ uint4 stage[4][NPW][2][64];

    const int lane    = threadIdx.x & 63;
    const int wv      = threadIdx.x >> 6;
    const int wave_id = (int)blockIdx.x * 4 + wv;
    const int f0      = __builtin_amdgcn_readfirstlane(wave_id * NPW);

    // ---- stage residual (and z) blocks: 1 dwordx4 wave-load per 1 KB ----
    {
        const uint4* rsrc = (const uint4*)(x0T16 + (size_t)f0 * DEG * B);
        uint4 r0 = rsrc[lane];
        uint4 r1 = rsrc[64 + lane];
        if (MODE != 0) {
            const uint4* zsrc = (const uint4*)(zin + (size_t)f0 * DEG * B);
            uint4 z0 = zsrc[lane];
            uint4 z1 = zsrc[64 + lane];
            stage[wv][0][0][lane] = z0;
            stage[wv][1][0][lane] = z1;
        }
        stage[wv][0][1][lane] = r0;
        stage[wv][1][1][lane] = r1;
        // no __syncthreads: wave-private region, compiler inserts waitcnt
    }

    // MODE 0 gather inputs (random lines; one-time layer, keep scalar)
    float g0[NPW][DEG];
    if (MODE == 0) {
        const int* ixp = in_ixs + f0 * DEG;                // s_load
        #pragma unroll
        for (int n = 0; n < NPW; ++n)
            #pragma unroll
            for (int d = 0; d < DEG; ++d)
                g0[n][d] = bf16_to_f32(
                    x0T16[(size_t)ixp[n * DEG + d] * B + lane]);
    }

    float oacc[NPW][DEG];   // outputs of both nodes (kept for MODE2 epilogue)

    #pragma unroll
    for (int n = 0; n < NPW; ++n) {
        const int f = f0 + n;

        // ---- unpack inputs + residual from wave-private LDS ----
        const bf16_t* zb = (const bf16_t*)&stage[wv][n][0][0];
        const bf16_t* rb = (const bf16_t*)&stage[wv][n][1][0];
        float g[DEG], r[DEG];
        #pragma unroll
        for (int d = 0; d < DEG; ++d) {
            g[d] = (MODE == 0) ? g0[n][d] : bf16_to_f32(zb[d * 64 + lane]);
            r[d] = bf16_to_f32(rb[d * 64 + lane]);
        }

        // ---- h = elu(g @ W1^T + b1) ----
        const unsigned* w1 = W1b + f * (H * DEG / 2);       // 64 dwords, s_load
        const float*   bb1 = b1 + f * H;
        float h[H];
        #pragma unroll
        for (int j = 0; j < H; ++j) {
            float acc = bb1[j];
            #pragma unroll
            for (int dp = 0; dp < DEG / 2; ++dp) {
                const unsigned u = w1[j * (DEG / 2) + dp];
                acc = fmaf(bfu_lo(u), g[2 * dp],     acc);
                acc = fmaf(bfu_hi(u), g[2 * dp + 1], acc);
            }
            h[j] = fast_elu(acc);
        }

        // ---- o = h @ W2^T + b2 + residual ----
        const unsigned* w2 = W2b + f * (DEG * H / 2);       // 64 dwords, s_load
        const float*   bb2 = b2 + f * DEG;
        #pragma unroll
        for (int d = 0; d < DEG; ++d) {
            float acc = bb2[d];
            #pragma unroll
            for (int jp = 0; jp < H / 2; ++jp) {
                const unsigned u = w2[d * (H / 2) + jp];
                acc = fmaf(bfu_lo(u), h[2 * jp],     acc);
                acc = fmaf(bfu_hi(u), h[2 * jp + 1], acc);
            }
            oacc[n][d] = acc + r[d];
        }

        if (MODE != 2) {
            // scatter into pre-permuted bf16 layout for next layer's seq read
            const int* invp = inv + f * DEG;                // s_load
            #pragma unroll
            for (int d = 0; d < DEG; ++d)
                zout[(size_t)invp[d] * B + lane] =
                    f32_to_bf16(oacc[n][d]);
        }
    }

    if (MODE == 2) {
        // block covers 8 nodes = 64 consecutive e; transpose via padded LDS
        // so the fp32 (B,E) store is full 128-B lines (was 32-B fragments).
        __shared__ float outs[64 * 65];                     // [e_local][b]
        #pragma unroll
        for (int n = 0; n < NPW; ++n)
            #pragma unroll
            for (int d = 0; d < DEG; ++d)
                outs[((wv * NPW + n) * DEG + d) * 65 + lane] = oacc[n][d];
        __syncthreads();

        const int b  = threadIdx.x >> 2;     // 0..63
        const int c  = threadIdx.x & 3;      // 0..3  (16 floats each)
        const int e0 = (int)blockIdx.x * 64;
        float* dst = out + (size_t)b * E_TOT + e0 + c * 16;
        #pragma unroll
        for (int q = 0; q < 4; ++q) {
            float4 v;
            v.x = outs[(c * 16 + q * 4 + 0) * 65 + b];
            v.y = outs[(c * 16 + q * 4 + 1) * 65 + b];
            v.z = outs[(c * 16 + q * 4 + 2) * 65 + b];
            v.w = outs[(c * 16 + q * 4 + 3) * 65 + b];
            ((float4*)dst)[q] = v;
        }
    }
}

extern "C" void kernel_launch(void* const* d_in, const int* in_sizes, int n_in,
                              void* d_out, int out_size, void* d_ws, size_t ws_size,
                              hipStream_t stream)
{
    const float* x0     = (const float*)d_in[0];
    const float* W1     = (const float*)d_in[1];
    const float* b1     = (const float*)d_in[2];
    const float* W2     = (const float*)d_in[3];
    const float* b2     = (const float*)d_in[4];
    const int*   in_ixs = (const int*)d_in[5];
    float* out = (float*)d_out;

    const size_t NEL = (size_t)E_TOT * B;        // 8.39M elements
    bf16_t*   x0T16 = (bf16_t*)d_ws;             // 16 MB
    bf16_t*   zA    = x0T16 + NEL;               // 16 MB
    bf16_t*   zB    = zA + NEL;                  // 16 MB
    int*      inv   = (int*)(zB + NEL);          // 512 KB
    unsigned* W1b   = (unsigned*)(inv + E_TOT);  // 4.2 MB
    unsigned* W2b   = W1b + F_NODES * H * DEG / 2;

    transpose_in_kernel<<<E_TOT / 64, 256, 0, stream>>>(x0, x0T16);
    build_inv_kernel<<<E_TOT / 256, 256, 0, stream>>>(in_ixs, inv);
    pack_weights_kernel<<<F_NODES * H * DEG / 2 / 256, 256, 0, stream>>>(
        W1, W2, W1b, W2b);

    const int grid = F_NODES / (4 * NPW);        // 2048 blocks

    layer_kernel<0><<<grid, 256, 0, stream>>>(
        nullptr, x0T16, W1b, b1, W2b, b2, in_ixs, inv, zA, nullptr);

    const bf16_t* cur = zA;
    bf16_t* nxt = zB;
    for (int l = 1; l < LAYERS - 1; ++l) {
        layer_kernel<1><<<grid, 256, 0, stream>>>(
            cur, x0T16, W1b, b1, W2b, b2, in_ixs, inv, nxt, nullptr);
        cur = nxt;
        nxt = (nxt == zA) ? zB : zA;
    }

    layer_kernel<2><<<grid, 256, 0, stream>>>(
        cur, x0T16, W1b, b1, W2b, b2, in_ixs, inv, nullptr, out);
}

// Round 5
// 312.929 us; speedup vs baseline: 1.0052x; 1.0052x over previous
//
#include <hip/hip_runtime.h>
#include <math.h>

#define F_NODES 16384
#define DEG 8
#define E_TOT (F_NODES * DEG)   // 131072
#define B 64
#define H 16
#define LAYERS 10
#define NPW 2                   // nodes per wave

typedef unsigned short bf16_t;

__device__ __forceinline__ bf16_t f32_to_bf16(float f)
{
    unsigned u = __float_as_uint(f);
    u = (u + 0x7FFFu + ((u >> 16) & 1u)) >> 16;   // round-to-nearest-even
    return (bf16_t)u;
}
__device__ __forceinline__ float bf16_to_f32(bf16_t h)
{
    return __uint_as_float((unsigned)h << 16);
}
// packed-pair unpack: elem0 = bits[15:0], elem1 = bits[31:16]
__device__ __forceinline__ float bfu_lo(unsigned u) { return __uint_as_float(u << 16); }
__device__ __forceinline__ float bfu_hi(unsigned u) { return __uint_as_float(u & 0xFFFF0000u); }

__device__ __forceinline__ float fast_elu(float x)
{
    float e = __builtin_amdgcn_exp2f(x * 1.44269504088896340736f) - 1.0f;
    return x > 0.0f ? x : e;
}

// ---------------------------------------------------------------------------
// Transpose x0 (B, E) fp32 -> x0T16 (E, B) bf16 (only copy of the residual).
// ---------------------------------------------------------------------------
__global__ __launch_bounds__(256) void transpose_in_kernel(
    const float* __restrict__ x0, bf16_t* __restrict__ xT16)
{
    __shared__ float tile[64 * 65];
    const int e0 = blockIdx.x * 64;
    const int c  = threadIdx.x & 63;
    const int r  = threadIdx.x >> 6;

    #pragma unroll
    for (int i = 0; i < 16; ++i) {
        const int b = r + i * 4;
        tile[c * 65 + b] = x0[(size_t)b * E_TOT + e0 + c];
    }
    __syncthreads();
    const int b = threadIdx.x & 63;
    #pragma unroll
    for (int i = 0; i < 16; ++i) {
        const int el = r + i * 4;
        xT16[(size_t)(e0 + el) * B + b] = f32_to_bf16(tile[el * 65 + b]);
    }
}

// inv[P[k]] = k  (P = flat in_ixs, a permutation of E)
__global__ __launch_bounds__(256) void build_inv_kernel(
    const int* __restrict__ in_ixs, int* __restrict__ inv)
{
    const int k = blockIdx.x * 256 + threadIdx.x;
    inv[in_ixs[k]] = k;
}

// Pack W1/W2 fp32 -> bf16 pairs (one dword = 2 consecutive weights).
__global__ __launch_bounds__(256) void pack_weights_kernel(
    const float* __restrict__ W1, const float* __restrict__ W2,
    unsigned* __restrict__ W1b, unsigned* __restrict__ W2b)
{
    const int i = blockIdx.x * 256 + threadIdx.x;
    float2 a = ((const float2*)W1)[i];
    W1b[i] = (unsigned)f32_to_bf16(a.x) | ((unsigned)f32_to_bf16(a.y) << 16);
    float2 c = ((const float2*)W2)[i];
    W2b[i] = (unsigned)f32_to_bf16(c.x) | ((unsigned)f32_to_bf16(c.y) << 16);
}

// ---------------------------------------------------------------------------
// One GSNN layer. z is PRE-PERMUTED (z[k] = x[P[k]]): sequential reads;
// the permutation is applied by scatter-stores via inv.
//   MODE 0: first  — gather bf16 x0T16[P[e]],           scatter bf16 z
//   MODE 1: middle — seq bf16 z in,                     scatter bf16 z
//   MODE 2: final  — seq bf16 z in,            fp32 (B,E) natural out
// v4: scatter stores cross-lane packed — 32 lanes store a DWORD each
// (full 4-B granules) instead of 64 lanes x 2-B shorts, attacking the 3.3x
// WRITE_SIZE amplification seen at the L2->EA boundary.
// ---------------------------------------------------------------------------
template <int MODE>
__global__ __launch_bounds__(256, 4) void layer_kernel(
    const bf16_t*  __restrict__ zin,    // (E, B) bf16 pre-permuted
    const bf16_t*  __restrict__ x0T16,  // (E, B) bf16
    const unsigned* __restrict__ W1b,   // (F, H, DEG/2) packed
    const float*   __restrict__ b1,     // (F, H)
    const unsigned* __restrict__ W2b,   // (F, DEG, H/2) packed
    const float*   __restrict__ b2,     // (F, DEG)
    const int*     __restrict__ in_ixs, // (F, DEG) = P
    const int*     __restrict__ inv,    // (E)      = P^-1
    bf16_t* __restrict__ zout,          // (E, B) bf16 pre-permuted
    float*  __restrict__ out)           // (B, E) fp32 final
{
    // wave-private staging: [wave][node][z=0/r=1][lane] -> 16 KB/block
    __shared__ uint4 stage[4][NPW][2][64];

    const int lane    = threadIdx.x & 63;
    const int wv      = threadIdx.x >> 6;
    const int wave_id = (int)blockIdx.x * 4 + wv;
    const int f0      = __builtin_amdgcn_readfirstlane(wave_id * NPW);

    // ---- stage residual (and z) blocks: 1 dwordx4 wave-load per 1 KB ----
    {
        const uint4* rsrc = (const uint4*)(x0T16 + (size_t)f0 * DEG * B);
        uint4 r0 = rsrc[lane];
        uint4 r1 = rsrc[64 + lane];
        if (MODE != 0) {
            const uint4* zsrc = (const uint4*)(zin + (size_t)f0 * DEG * B);
            uint4 z0 = zsrc[lane];
            uint4 z1 = zsrc[64 + lane];
            stage[wv][0][0][lane] = z0;
            stage[wv][1][0][lane] = z1;
        }
        stage[wv][0][1][lane] = r0;
        stage[wv][1][1][lane] = r1;
        // no __syncthreads: wave-private region, compiler inserts waitcnt
    }

    // MODE 0 gather inputs (random lines; one-time layer, keep scalar)
    float g0[NPW][DEG];
    if (MODE == 0) {
        const int* ixp = in_ixs + f0 * DEG;                // s_load
        #pragma unroll
        for (int n = 0; n < NPW; ++n)
            #pragma unroll
            for (int d = 0; d < DEG; ++d)
                g0[n][d] = bf16_to_f32(
                    x0T16[(size_t)ixp[n * DEG + d] * B + lane]);
    }

    float oacc[NPW][DEG];   // outputs of both nodes (kept for MODE2 epilogue)

    #pragma unroll
    for (int n = 0; n < NPW; ++n) {
        const int f = f0 + n;

        // ---- unpack inputs + residual from wave-private LDS ----
        const bf16_t* zb = (const bf16_t*)&stage[wv][n][0][0];
        const bf16_t* rb = (const bf16_t*)&stage[wv][n][1][0];
        float g[DEG], r[DEG];
        #pragma unroll
        for (int d = 0; d < DEG; ++d) {
            g[d] = (MODE == 0) ? g0[n][d] : bf16_to_f32(zb[d * 64 + lane]);
            r[d] = bf16_to_f32(rb[d * 64 + lane]);
        }

        // ---- h = elu(g @ W1^T + b1) ----
        const unsigned* w1 = W1b + f * (H * DEG / 2);       // 64 dwords, s_load
        const float*   bb1 = b1 + f * H;
        float h[H];
        #pragma unroll
        for (int j = 0; j < H; ++j) {
            float acc = bb1[j];
            #pragma unroll
            for (int dp = 0; dp < DEG / 2; ++dp) {
                const unsigned u = w1[j * (DEG / 2) + dp];
                acc = fmaf(bfu_lo(u), g[2 * dp],     acc);
                acc = fmaf(bfu_hi(u), g[2 * dp + 1], acc);
            }
            h[j] = fast_elu(acc);
        }

        // ---- o = h @ W2^T + b2 + residual ----
        const unsigned* w2 = W2b + f * (DEG * H / 2);       // 64 dwords, s_load
        const float*   bb2 = b2 + f * DEG;
        #pragma unroll
        for (int d = 0; d < DEG; ++d) {
            float acc = bb2[d];
            #pragma unroll
            for (int jp = 0; jp < H / 2; ++jp) {
                const unsigned u = w2[d * (H / 2) + jp];
                acc = fmaf(bfu_lo(u), h[2 * jp],     acc);
                acc = fmaf(bfu_hi(u), h[2 * jp + 1], acc);
            }
            oacc[n][d] = acc + r[d];
        }

        if (MODE != 2) {
            // cross-lane pack: lane i<32 gathers the dword for bytes
            // [4i..4i+3] of line d (= values of lanes 2i, 2i+1), then 32
            // lanes store dwords — full 4-B write granules, same 128-B line.
            const int* invp = inv + f * DEG;                // s_load
            int dwc[DEG];
            #pragma unroll
            for (int d = 0; d < DEG; ++d) {
                int us = (int)f32_to_bf16(oacc[n][d]);      // low 16 bits
                int pr = __shfl_xor(us, 1);
                int dw = us | (pr << 16);                   // valid on even lanes
                dwc[d] = __builtin_amdgcn_ds_bpermute(
                    ((2 * lane) & 63) << 2, dw);            // lane i <- lane 2i
            }
            if (lane < 32) {
                #pragma unroll
                for (int d = 0; d < DEG; ++d)
                    ((unsigned*)zout)[(size_t)invp[d] * (B / 2) + lane] =
                        (unsigned)dwc[d];
            }
        }
    }

    if (MODE == 2) {
        // block covers 8 nodes = 64 consecutive e; transpose via padded LDS
        // so the fp32 (B,E) store is full 128-B lines (was 32-B fragments).
        __shared__ float outs[64 * 65];                     // [e_local][b]
        #pragma unroll
        for (int n = 0; n < NPW; ++n)
            #pragma unroll
            for (int d = 0; d < DEG; ++d)
                outs[((wv * NPW + n) * DEG + d) * 65 + lane] = oacc[n][d];
        __syncthreads();

        const int b  = threadIdx.x >> 2;     // 0..63
        const int c  = threadIdx.x & 3;      // 0..3  (16 floats each)
        const int e0 = (int)blockIdx.x * 64;
        float* dst = out + (size_t)b * E_TOT + e0 + c * 16;
        #pragma unroll
        for (int q = 0; q < 4; ++q) {
            float4 v;
            v.x = outs[(c * 16 + q * 4 + 0) * 65 + b];
            v.y = outs[(c * 16 + q * 4 + 1) * 65 + b];
            v.z = outs[(c * 16 + q * 4 + 2) * 65 + b];
            v.w = outs[(c * 16 + q * 4 + 3) * 65 + b];
            ((float4*)dst)[q] = v;
        }
    }
}

extern "C" void kernel_launch(void* const* d_in, const int* in_sizes, int n_in,
                              void* d_out, int out_size, void* d_ws, size_t ws_size,
                              hipStream_t stream)
{
    const float* x0     = (const float*)d_in[0];
    const float* W1     = (const float*)d_in[1];
    const float* b1     = (const float*)d_in[2];
    const float* W2     = (const float*)d_in[3];
    const float* b2     = (const float*)d_in[4];
    const int*   in_ixs = (const int*)d_in[5];
    float* out = (float*)d_out;

    const size_t NEL = (size_t)E_TOT * B;        // 8.39M elements
    bf16_t*   x0T16 = (bf16_t*)d_ws;             // 16 MB
    bf16_t*   zA    = x0T16 + NEL;               // 16 MB
    bf16_t*   zB    = zA + NEL;                  // 16 MB
    int*      inv   = (int*)(zB + NEL);          // 512 KB
    unsigned* W1b   = (unsigned*)(inv + E_TOT);  // 4.2 MB
    unsigned* W2b   = W1b + F_NODES * H * DEG / 2;

    transpose_in_kernel<<<E_TOT / 64, 256, 0, stream>>>(x0, x0T16);
    build_inv_kernel<<<E_TOT / 256, 256, 0, stream>>>(in_ixs, inv);
    pack_weights_kernel<<<F_NODES * H * DEG / 2 / 256, 256, 0, stream>>>(
        W1, W2, W1b, W2b);

    const int grid = F_NODES / (4 * NPW);        // 2048 blocks

    layer_kernel<0><<<grid, 256, 0, stream>>>(
        nullptr, x0T16, W1b, b1, W2b, b2, in_ixs, inv, zA, nullptr);

    const bf16_t* cur = zA;
    bf16_t* nxt = zB;
    for (int l = 1; l < LAYERS - 1; ++l) {
        layer_kernel<1><<<grid, 256, 0, stream>>>(
            cur, x0T16, W1b, b1, W2b, b2, in_ixs, inv, nxt, nullptr);
        cur = nxt;
        nxt = (nxt == zA) ? zB : zA;
    }

    layer_kernel<2><<<grid, 256, 0, stream>>>(
        cur, x0T16, W1b, b1, W2b, b2, in_ixs, inv, nullptr, out);
}